// Round 10
// baseline (203.956 us; speedup 1.0000x reference)
//
#include <hip/hip_runtime.h>

#define CT 256
#define KDIM 2304
#define COLP 296         // padded col row stride in shorts

typedef unsigned short u16;
typedef __attribute__((ext_vector_type(8))) short bf16x8;
typedef __attribute__((ext_vector_type(4))) float f32x4;
typedef __fp16 fp16x2 __attribute__((ext_vector_type(2)));

__device__ __forceinline__ unsigned f2b(float f) {       // f32 -> bf16 bits, RTE
    unsigned u = __float_as_uint(f);
    u += 0x7fffu + ((u >> 16) & 1u);
    return u >> 16;
}
__device__ __forceinline__ float lo_bf(unsigned u) { return __uint_as_float(u << 16); }
__device__ __forceinline__ float hi_bf(unsigned u) { return __uint_as_float(u & 0xffff0000u); }

// Fused prep: blocks [0,2048) = x -> xi (bf16 interleaved-8); [2048,2336) = W -> pw.
__global__ __launch_bounds__(256) void k_prep(const float* __restrict__ x, uint4* __restrict__ xi,
                                              const float* __restrict__ wgt, uint4* __restrict__ pw)
{
    if (blockIdx.x < 2048) {
        int u = blockIdx.x * 256 + threadIdx.x;        // [0, 524288)
        int bcg = u >> 12, p = u & 4095;
        const float* xp = x + (((size_t)bcg) << 15) + p;
        unsigned r[4];
#pragma unroll
        for (int i = 0; i < 4; ++i) {
            float a = xp[(size_t)(2 * i) << 12];
            float c = xp[(size_t)(2 * i + 1) << 12];
            r[i] = f2b(a) | (f2b(c) << 16);
        }
        uint4 o; o.x = r[0]; o.y = r[1]; o.z = r[2]; o.w = r[3];
        xi[u] = o;
    } else {
        int u = (blockIdx.x - 2048) * 256 + threadIdx.x;   // [0, 73728)
        int kc = u >> 10, rm = u & 1023;
        int m = rm >> 2, j = rm & 3;
        int round = kc / 9, tap = kc - round * 9;
        const float* src = wgt + (size_t)m * KDIM + tap;
        int c0 = round * 32 + j * 8;
        unsigned q[4];
#pragma unroll
        for (int i = 0; i < 4; ++i) {
            float a = src[(size_t)(c0 + 2 * i) * 9];
            float c = src[(size_t)(c0 + 2 * i + 1) * 9];
            q[i] = f2b(a) | (f2b(c) << 16);
        }
        uint4 o; o.x = q[0]; o.y = q[1]; o.z = q[2]; o.w = q[3];
        pw[u] = o;
    }
}

// Fused: deformable unfold (LDS gather, prefetched double-superplane stages) + attention
// + MFMA GEMM + GN partials. Grid 512: bx = rowblk*2 + half; 512 threads = 8 waves.
__global__ __launch_bounds__(512, 2) void k_main(const uint4* __restrict__ xi, const float* __restrict__ off,
                                                 const uint4* __restrict__ pw, const float* __restrict__ att_w,
                                                 const float* __restrict__ att_b,
                                                 float* __restrict__ outp, float* __restrict__ gnpart)
{
    __shared__ uint2 s_wt[288];        // bilinear corner weights as 4 x f16
    __shared__ int2 s_off[288];        // packed corner positions
    __shared__ u16 Xs[2 * 7680];       // TWO superplanes: 2 x (<=15 rows x 64 pos x 8 ch)
    __shared__ u16 col[32 * COLP];     // 32 n x 288 k (padded)
    __shared__ float s_att[32];

    int rowblk = blockIdx.x >> 1, half = blockIdx.x & 1;
    int b = rowblk >> 6, h = rowblk & 63, n0 = half * 32;
    int tid = threadIdx.x;
    int lane = tid & 63, w = tid >> 6;
    int l15 = lane & 15, kb = lane >> 4;
    int wm = w * 32;

    // bilinear coords for this block's 32 positions
    for (int e = tid; e < 288; e += 512) {
        int kk = e >> 5, wl = e & 31;
        int ww_ = n0 + wl;
        int ky = kk / 3, kx = kk - ky * 3;
        float dy = off[((size_t)(b * 18 + 2 * kk) * 64 + h) * 64 + ww_];
        float dx = off[((size_t)(b * 18 + 2 * kk + 1) * 64 + h) * 64 + ww_];
        float py = (float)(h + ky - 1) + dy;
        float px = (float)(ww_ + kx - 1) + dx;
        float y0f = floorf(py), x0f = floorf(px);
        int y0 = (int)y0f, x0 = (int)x0f;
        float fy = py - y0f, fx = px - x0f;
        float vy0 = (y0 >= 0 && y0 < 64) ? 1.f : 0.f;
        float vy1 = (y0 >= -1 && y0 < 63) ? 1.f : 0.f;
        float vx0 = (x0 >= 0 && x0 < 64) ? 1.f : 0.f;
        float vx1 = (x0 >= -1 && x0 < 63) ? 1.f : 0.f;
        float w0 = (1.f - fy) * (1.f - fx) * vy0 * vx0;
        float w1 = (1.f - fy) * fx * vy0 * vx1;
        float w2 = fy * (1.f - fx) * vy1 * vx0;
        float w3 = fy * fx * vy1 * vx1;
        fp16x2 pA = __builtin_amdgcn_cvt_pkrtz(w0, w1);
        fp16x2 pB = __builtin_amdgcn_cvt_pkrtz(w2, w3);
        uint2 wp;
        wp.x = __builtin_bit_cast(unsigned, pA);
        wp.y = __builtin_bit_cast(unsigned, pB);
        int yc0 = min(max(y0, 0), 63), yc1 = min(max(y0 + 1, 0), 63);
        int xc0 = min(max(x0, 0), 63), xc1 = min(max(x0 + 1, 0), 63);
        s_wt[e] = wp;
        s_off[e] = make_int2((yc0 * 64 + xc0) | ((yc0 * 64 + xc1) << 16),
                             (yc1 * 64 + xc0) | ((yc1 * 64 + xc1) << 16));
    }

    int r0 = max(0, h - 7), r1 = min(63, h + 7);
    int nrows = r1 - r0 + 1, nw = nrows * 64, rbase = r0 * 64;
    int nw2 = nw * 2;
    size_t xib = (size_t)(b * 32) << 12;               // base of this image's 32 superplanes

    float att_acc = 0.f;
    f32x4 acc[2][2];
#pragma unroll
    for (int mt = 0; mt < 2; ++mt)
#pragma unroll
        for (int nt = 0; nt < 2; ++nt) acc[mt][nt] = (f32x4){0.f, 0.f, 0.f, 0.f};

    // prefetch stage 0 (cgs 0,1) into registers
    uint4 pf[4];
#pragma unroll
    for (int i = 0; i < 4; ++i) {
        int e = tid + i * 512;
        int cgl = (e >= nw) ? 1 : 0;
        int idx = e - cgl * nw;
        if (e < nw2) pf[i] = xi[xib + ((size_t)cgl << 12) + rbase + idx];
    }

    for (int round = 0; round < 8; ++round) {
        for (int s2 = 0; s2 < 2; ++s2) {
            int stage = round * 2 + s2;
            __syncthreads();           // prev gather done reading Xs; (s2==0) prev MFMA done reading col
#pragma unroll
            for (int i = 0; i < 4; ++i) {
                int e = tid + i * 512;
                if (e < nw2) ((uint4*)Xs)[e] = pf[i];
            }
            __syncthreads();           // Xs ready
            // issue prefetch for next stage (clamped; loads in flight during gather)
            int ns = min(stage + 1, 15);
            size_t nb0 = xib + ((size_t)(ns * 2) << 12) + rbase;
#pragma unroll
            for (int i = 0; i < 4; ++i) {
                int e = tid + i * 512;
                int cgl = (e >= nw) ? 1 : 0;
                int idx = e - cgl * nw;
                if (e < nw2) pf[i] = xi[nb0 + ((size_t)cgl << 12) + idx];
            }
            // gather: 576 iters = 2 cgs x 9 taps x 32 n
            for (int it = tid; it < 576; it += 512) {
                int cgl = (it >= 288) ? 1 : 0;
                int it2 = it - cgl * 288;
                int tap = it2 >> 5, nn = it2 & 31;
                int xsb = cgl * nw * 8;
                size_t gfall = xib + ((size_t)(stage * 2 + cgl) << 12);
                uint2 wp = s_wt[it2];
                fp16x2 wA = __builtin_bit_cast(fp16x2, wp.x);
                fp16x2 wB = __builtin_bit_cast(fp16x2, wp.y);
                float wx = (float)wA[0], wy = (float)wA[1];
                float wz = (float)wB[0], ww2 = (float)wB[1];
                int2 of = s_off[it2];
                int P00 = of.x & 0xffff, P01 = (of.x >> 16) & 0xffff;
                int P10 = of.y & 0xffff, P11 = (of.y >> 16) & 0xffff;
                uint4 c00, c01, c10, c11;
                int Q;
                Q = P00 - rbase;
                if ((unsigned)Q < (unsigned)nw) c00 = *(const uint4*)&Xs[xsb + Q * 8]; else c00 = xi[gfall + P00];
                Q = P01 - rbase;
                if ((unsigned)Q < (unsigned)nw) c01 = *(const uint4*)&Xs[xsb + Q * 8]; else c01 = xi[gfall + P01];
                Q = P10 - rbase;
                if ((unsigned)Q < (unsigned)nw) c10 = *(const uint4*)&Xs[xsb + Q * 8]; else c10 = xi[gfall + P10];
                Q = P11 - rbase;
                if ((unsigned)Q < (unsigned)nw) c11 = *(const uint4*)&Xs[xsb + Q * 8]; else c11 = xi[gfall + P11];
                const unsigned* a00 = (const unsigned*)&c00;
                const unsigned* a01 = (const unsigned*)&c01;
                const unsigned* a10 = (const unsigned*)&c10;
                const unsigned* a11 = (const unsigned*)&c11;
                unsigned o[4];
#pragma unroll
                for (int q = 0; q < 4; ++q) {
                    float v0 = wx * lo_bf(a00[q]) + wy * lo_bf(a01[q]) + wz * lo_bf(a10[q]) + ww2 * lo_bf(a11[q]);
                    float v1 = wx * hi_bf(a00[q]) + wy * hi_bf(a01[q]) + wz * hi_bf(a10[q]) + ww2 * hi_bf(a11[q]);
                    o[q] = f2b(v0) | (f2b(v1) << 16);
                }
                uint4 ov; ov.x = o[0]; ov.y = o[1]; ov.z = o[2]; ov.w = o[3];
                int sp = s2 * 2 + cgl;
                *(uint4*)&col[nn * COLP + tap * 32 + sp * 8] = ov;
            }
        }
        __syncthreads();               // full 288-k col slice ready

        // attention tap-max + dot: wave 0 only (others proceed to MFMA)
        if (tid < 64) {
            int nn = tid >> 1, h2 = tid & 1;
#pragma unroll
            for (int sp = 0; sp < 4; ++sp) {
                const u16* base = &col[nn * COLP + sp * 8 + h2 * 4];
                float m0 = -1e30f, m1 = -1e30f, m2 = -1e30f, m3 = -1e30f;
#pragma unroll
                for (int t = 0; t < 9; ++t) {
                    uint2 v = *(const uint2*)(base + t * 32);
                    m0 = fmaxf(m0, lo_bf(v.x)); m1 = fmaxf(m1, hi_bf(v.x));
                    m2 = fmaxf(m2, lo_bf(v.y)); m3 = fmaxf(m3, hi_bf(v.y));
                }
                int cb = round * 32 + sp * 8 + h2 * 4;
                att_acc += att_w[cb] * m0 + att_w[cb + 1] * m1 + att_w[cb + 2] * m2 + att_w[cb + 3] * m3;
            }
        }

        // MFMA phase: no internal barriers (col stable; A streamed from L2)
#pragma unroll
        for (int ts = 0; ts < 9; ++ts) {
            int kc = round * 9 + ts;
            bf16x8 bf[2];
#pragma unroll
            for (int nt = 0; nt < 2; ++nt)
                bf[nt] = *(const bf16x8*)&col[(nt * 16 + l15) * COLP + ts * 32 + kb * 8];
#pragma unroll
            for (int mt = 0; mt < 2; ++mt) {
                uint4 a = pw[(size_t)kc * 1024 + (wm + mt * 16 + l15) * 4 + kb];
                bf16x8 af = __builtin_bit_cast(bf16x8, a);
#pragma unroll
                for (int nt = 0; nt < 2; ++nt)
                    acc[mt][nt] = __builtin_amdgcn_mfma_f32_16x16x32_bf16(af, bf[nt], acc[mt][nt], 0, 0, 0);
            }
        }
    }

    // finalize attention (wave 0), broadcast via LDS
    if (tid < 64) {
        float v = att_acc + __shfl_xor(att_acc, 1);
        if ((tid & 1) == 0) s_att[tid >> 1] = 1.f / (1.f + expf(-(v + att_b[0])));
    }
    __syncthreads();

    float attn[2];
#pragma unroll
    for (int nt = 0; nt < 2; ++nt) attn[nt] = s_att[nt * 16 + l15];

    // epilogue: scale by att, write out, GN partial sums
#pragma unroll
    for (int mt = 0; mt < 2; ++mt) {
        float s1 = 0.f, s2 = 0.f;
#pragma unroll
        for (int nt = 0; nt < 2; ++nt)
#pragma unroll
            for (int r = 0; r < 4; ++r) {
                float v = acc[mt][nt][r] * attn[nt];
                int m = wm + mt * 16 + kb * 4 + r;
                outp[(((size_t)(b * CT + m)) << 12) + h * 64 + n0 + nt * 16 + l15] = v;
                s1 += v; s2 += v * v;
            }
#pragma unroll
        for (int d = 1; d <= 16; d <<= 1) {
            s1 += __shfl_xor(s1, d);
            s2 += __shfl_xor(s2, d);
        }
        if ((lane & 31) == 0) {
            int gidx = w * 4 + mt * 2 + (kb >> 1);
            gnpart[blockIdx.x * 64 + gidx * 2] = s1;
            gnpart[blockIdx.x * 64 + gidx * 2 + 1] = s2;
        }
    }
}

// Fused GroupNorm: one block per (b,g); reduce 128 partial pairs -> stats -> normalize 32768 floats.
__global__ __launch_bounds__(256) void k_gn(const float* __restrict__ gnpart, const float* __restrict__ gamma,
                                            const float* __restrict__ beta, float* __restrict__ outp)
{
    __shared__ float rs1[128], rs2[128];
    __shared__ float s_stat[2];
    int bg = blockIdx.x;               // b = bg>>5, g = bg&31
    int b = bg >> 5, g = bg & 31;
    int tid = threadIdx.x;
    if (tid < 128) {
        int blk = (b * 64 + (tid >> 1)) * 2 + (tid & 1);
        rs1[tid] = gnpart[blk * 64 + g * 2];
        rs2[tid] = gnpart[blk * 64 + g * 2 + 1];
    }
    __syncthreads();
    if (tid < 64) {
        float a = rs1[tid] + rs1[tid + 64];
        float c = rs2[tid] + rs2[tid + 64];
#pragma unroll
        for (int d = 1; d <= 32; d <<= 1) {
            a += __shfl_xor(a, d);
            c += __shfl_xor(c, d);
        }
        if (tid == 0) {
            float mean = a * (1.f / 32768.f);
            float var = c * (1.f / 32768.f) - mean * mean;
            s_stat[0] = mean;
            s_stat[1] = rsqrtf(var + 1e-5f);
        }
    }
    __syncthreads();
    float mean = s_stat[0], rstd = s_stat[1];
    float4* p4 = (float4*)(outp + ((size_t)(b * CT + g * 8) << 12));
    for (int i = tid; i < 8192; i += 256) {
        int c = g * 8 + (i >> 10);
        float ga = gamma[c], be = beta[c];
        float4 v = p4[i];
        float4 r;
        r.x = fmaxf((v.x - mean) * rstd * ga + be, 0.f);
        r.y = fmaxf((v.y - mean) * rstd * ga + be, 0.f);
        r.z = fmaxf((v.z - mean) * rstd * ga + be, 0.f);
        r.w = fmaxf((v.w - mean) * rstd * ga + be, 0.f);
        p4[i] = r;
    }
}

extern "C" void kernel_launch(void* const* d_in, const int* in_sizes, int n_in,
                              void* d_out, int out_size, void* d_ws, size_t ws_size,
                              hipStream_t stream)
{
    const float* x = (const float*)d_in[0];
    const float* off = (const float*)d_in[1];
    const float* wgt = (const float*)d_in[2];
    const float* attw = (const float*)d_in[3];
    const float* attb = (const float*)d_in[4];
    const float* gamma = (const float*)d_in[5];
    const float* beta = (const float*)d_in[6];
    float* outp = (float*)d_out;

    char* ws = (char*)d_ws;
    uint4* xi = (uint4*)ws;                          // 8.39 MB
    uint4* pw = (uint4*)(ws + 8388608);              // 1.18 MB
    float* gnpart = (float*)(ws + 9568256);          // 512*64 f32 = 128 KB

    k_prep<<<dim3(2336), dim3(256), 0, stream>>>(x, xi, wgt, pw);
    k_main<<<dim3(512), dim3(512), 0, stream>>>(xi, off, pw, attw, attb, outp, gnpart);
    k_gn<<<dim3(128), dim3(256), 0, stream>>>(gnpart, gamma, beta, outp);
}

// Round 11
// 150.124 us; speedup vs baseline: 1.3586x; 1.3586x over previous
//
#include <hip/hip_runtime.h>

#define CT 256
#define KDIM 2304
#define COLP 296         // padded col row stride in shorts

typedef unsigned short u16;
typedef __attribute__((ext_vector_type(8))) short bf16x8;
typedef __attribute__((ext_vector_type(4))) float f32x4;
typedef __fp16 fp16x2 __attribute__((ext_vector_type(2)));

__device__ __forceinline__ unsigned f2b(float f) {       // f32 -> bf16 bits, RTE
    unsigned u = __float_as_uint(f);
    u += 0x7fffu + ((u >> 16) & 1u);
    return u >> 16;
}
__device__ __forceinline__ float lo_bf(unsigned u) { return __uint_as_float(u << 16); }
__device__ __forceinline__ float hi_bf(unsigned u) { return __uint_as_float(u & 0xffff0000u); }

// async global->LDS DMA, 16B per lane; LDS dest must be wave-uniform base + lane*16
__device__ __forceinline__ void gload_lds16(const uint4* g, u16* l) {
    __builtin_amdgcn_global_load_lds((const __attribute__((address_space(1))) void*)g,
                                     (__attribute__((address_space(3))) void*)l, 16, 0, 0);
}

// Fused prep: blocks [0,2048) = x -> xi (bf16 interleaved-8); [2048,2336) = W -> pw.
__global__ __launch_bounds__(256) void k_prep(const float* __restrict__ x, uint4* __restrict__ xi,
                                              const float* __restrict__ wgt, uint4* __restrict__ pw)
{
    if (blockIdx.x < 2048) {
        int u = blockIdx.x * 256 + threadIdx.x;        // [0, 524288)
        int bcg = u >> 12, p = u & 4095;
        const float* xp = x + (((size_t)bcg) << 15) + p;
        unsigned r[4];
#pragma unroll
        for (int i = 0; i < 4; ++i) {
            float a = xp[(size_t)(2 * i) << 12];
            float c = xp[(size_t)(2 * i + 1) << 12];
            r[i] = f2b(a) | (f2b(c) << 16);
        }
        uint4 o; o.x = r[0]; o.y = r[1]; o.z = r[2]; o.w = r[3];
        xi[u] = o;
    } else {
        int u = (blockIdx.x - 2048) * 256 + threadIdx.x;   // [0, 73728)
        int kc = u >> 10, rm = u & 1023;
        int m = rm >> 2, j = rm & 3;
        int round = kc / 9, tap = kc - round * 9;
        const float* src = wgt + (size_t)m * KDIM + tap;
        int c0 = round * 32 + j * 8;
        unsigned q[4];
#pragma unroll
        for (int i = 0; i < 4; ++i) {
            float a = src[(size_t)(c0 + 2 * i) * 9];
            float c = src[(size_t)(c0 + 2 * i + 1) * 9];
            q[i] = f2b(a) | (f2b(c) << 16);
        }
        uint4 o; o.x = q[0]; o.y = q[1]; o.z = q[2]; o.w = q[3];
        pw[u] = o;
    }
}

// Fused: deformable unfold (DMA-staged LDS gather) + attention + MFMA GEMM + GN partials.
// Grid 512: bx = rowblk*2 + half; 512 threads = 8 waves. Stage = 2 channel-groups (16 stages),
// Xs double-buffered, next stage prefetched via global_load_lds during current gather.
__global__ __launch_bounds__(512, 2) void k_main(const uint4* __restrict__ xi, const float* __restrict__ off,
                                                 const uint4* __restrict__ pw, const float* __restrict__ att_w,
                                                 const float* __restrict__ att_b,
                                                 float* __restrict__ outp, float* __restrict__ gnpart)
{
    __shared__ uint2 s_wt[288];        // bilinear corner weights as 4 x f16
    __shared__ int2 s_off[288];        // packed corner positions
    __shared__ u16 Xs[4 * 6656];       // [buf][cgl] planes: <=13 rows x 64 pos x 8 ch each
    __shared__ u16 col[32 * COLP];     // 32 n x 288 k (padded)
    __shared__ float s_att[32];

    int rowblk = blockIdx.x >> 1, half = blockIdx.x & 1;
    int b = rowblk >> 6, h = rowblk & 63, n0 = half * 32;
    int tid = threadIdx.x;
    int lane = tid & 63, w = tid >> 6;
    int l15 = lane & 15, kb = lane >> 4;
    int wm = w * 32;

    // bilinear coords for this block's 32 positions
    for (int e = tid; e < 288; e += 512) {
        int kk = e >> 5, wl = e & 31;
        int ww_ = n0 + wl;
        int ky = kk / 3, kx = kk - ky * 3;
        float dy = off[((size_t)(b * 18 + 2 * kk) * 64 + h) * 64 + ww_];
        float dx = off[((size_t)(b * 18 + 2 * kk + 1) * 64 + h) * 64 + ww_];
        float py = (float)(h + ky - 1) + dy;
        float px = (float)(ww_ + kx - 1) + dx;
        float y0f = floorf(py), x0f = floorf(px);
        int y0 = (int)y0f, x0 = (int)x0f;
        float fy = py - y0f, fx = px - x0f;
        float vy0 = (y0 >= 0 && y0 < 64) ? 1.f : 0.f;
        float vy1 = (y0 >= -1 && y0 < 63) ? 1.f : 0.f;
        float vx0 = (x0 >= 0 && x0 < 64) ? 1.f : 0.f;
        float vx1 = (x0 >= -1 && x0 < 63) ? 1.f : 0.f;
        float w0 = (1.f - fy) * (1.f - fx) * vy0 * vx0;
        float w1 = (1.f - fy) * fx * vy0 * vx1;
        float w2 = fy * (1.f - fx) * vy1 * vx0;
        float w3 = fy * fx * vy1 * vx1;
        fp16x2 pA = __builtin_amdgcn_cvt_pkrtz(w0, w1);
        fp16x2 pB = __builtin_amdgcn_cvt_pkrtz(w2, w3);
        uint2 wp;
        wp.x = __builtin_bit_cast(unsigned, pA);
        wp.y = __builtin_bit_cast(unsigned, pB);
        int yc0 = min(max(y0, 0), 63), yc1 = min(max(y0 + 1, 0), 63);
        int xc0 = min(max(x0, 0), 63), xc1 = min(max(x0 + 1, 0), 63);
        s_wt[e] = wp;
        s_off[e] = make_int2((yc0 * 64 + xc0) | ((yc0 * 64 + xc1) << 16),
                             (yc1 * 64 + xc0) | ((yc1 * 64 + xc1) << 16));
    }

    int r0 = max(0, h - 6), r1 = min(63, h + 6);
    int nrows = r1 - r0 + 1, nw = nrows * 64, rbase = r0 * 64;
    size_t xib = (size_t)(b * 32) << 12;               // base of this image's 32 superplanes

    float att_acc = 0.f;
    f32x4 acc[2][2];
#pragma unroll
    for (int mt = 0; mt < 2; ++mt)
#pragma unroll
        for (int nt = 0; nt < 2; ++nt) acc[mt][nt] = (f32x4){0.f, 0.f, 0.f, 0.f};

    // issue DMA for stage 0 into buf 0
#pragma unroll
    for (int cgl = 0; cgl < 2; ++cgl)
        for (int e = tid; e < nw; e += 512)
            gload_lds16(&xi[xib + ((size_t)cgl << 12) + rbase + e], &Xs[(cgl * 6656 + e * 8)]);

    for (int stage = 0; stage < 16; ++stage) {
        int buf = stage & 1;
        int s2 = stage & 1;            // col sp-pair selector within round
        __syncthreads();               // Xs[buf] DMA drained; prev gather (read buf^1) done
        // issue DMA for next stage into buf^1 (drains at next barrier, covered by this gather)
        if (stage < 15) {
            size_t nb = xib + ((size_t)((stage + 1) * 2) << 12) + rbase;
#pragma unroll
            for (int cgl = 0; cgl < 2; ++cgl)
                for (int e = tid; e < nw; e += 512)
                    gload_lds16(&xi[nb + ((size_t)cgl << 12) + e],
                                &Xs[(((buf ^ 1) * 2 + cgl) * 6656 + e * 8)]);
        }
        // gather: 576 items = 2 cgs x 9 taps x 32 n, from Xs[buf]
        for (int it = tid; it < 576; it += 512) {
            int cgl = (it >= 288) ? 1 : 0;
            int it2 = it - cgl * 288;
            int tap = it2 >> 5, nn = it2 & 31;
            int xsb = (buf * 2 + cgl) * 6656;
            size_t gfall = xib + ((size_t)(stage * 2 + cgl) << 12);
            uint2 wp = s_wt[it2];
            fp16x2 wA = __builtin_bit_cast(fp16x2, wp.x);
            fp16x2 wB = __builtin_bit_cast(fp16x2, wp.y);
            float wx = (float)wA[0], wy = (float)wA[1];
            float wz = (float)wB[0], ww2 = (float)wB[1];
            int2 of = s_off[it2];
            int P00 = of.x & 0xffff, P01 = (of.x >> 16) & 0xffff;
            int P10 = of.y & 0xffff, P11 = (of.y >> 16) & 0xffff;
            uint4 c00, c01, c10, c11;
            int Q;
            Q = P00 - rbase;
            if ((unsigned)Q < (unsigned)nw) c00 = *(const uint4*)&Xs[xsb + Q * 8]; else c00 = xi[gfall + P00];
            Q = P01 - rbase;
            if ((unsigned)Q < (unsigned)nw) c01 = *(const uint4*)&Xs[xsb + Q * 8]; else c01 = xi[gfall + P01];
            Q = P10 - rbase;
            if ((unsigned)Q < (unsigned)nw) c10 = *(const uint4*)&Xs[xsb + Q * 8]; else c10 = xi[gfall + P10];
            Q = P11 - rbase;
            if ((unsigned)Q < (unsigned)nw) c11 = *(const uint4*)&Xs[xsb + Q * 8]; else c11 = xi[gfall + P11];
            const unsigned* a00 = (const unsigned*)&c00;
            const unsigned* a01 = (const unsigned*)&c01;
            const unsigned* a10 = (const unsigned*)&c10;
            const unsigned* a11 = (const unsigned*)&c11;
            unsigned o[4];
#pragma unroll
            for (int q = 0; q < 4; ++q) {
                float v0 = wx * lo_bf(a00[q]) + wy * lo_bf(a01[q]) + wz * lo_bf(a10[q]) + ww2 * lo_bf(a11[q]);
                float v1 = wx * hi_bf(a00[q]) + wy * hi_bf(a01[q]) + wz * hi_bf(a10[q]) + ww2 * hi_bf(a11[q]);
                o[q] = f2b(v0) | (f2b(v1) << 16);
            }
            uint4 ov; ov.x = o[0]; ov.y = o[1]; ov.z = o[2]; ov.w = o[3];
            int sp = s2 * 2 + cgl;
            *(uint4*)&col[nn * COLP + tap * 32 + sp * 8] = ov;
        }

        if (stage & 1) {               // full 288-k col slice ready -> att + MFMA
            int round = stage >> 1;
            __syncthreads();

            // attention tap-max + dot: wave 0 only (others proceed to MFMA)
            if (tid < 64) {
                int nn = tid >> 1, h2 = tid & 1;
#pragma unroll
                for (int sp = 0; sp < 4; ++sp) {
                    const u16* base = &col[nn * COLP + sp * 8 + h2 * 4];
                    float m0 = -1e30f, m1 = -1e30f, m2 = -1e30f, m3 = -1e30f;
#pragma unroll
                    for (int t = 0; t < 9; ++t) {
                        uint2 v = *(const uint2*)(base + t * 32);
                        m0 = fmaxf(m0, lo_bf(v.x)); m1 = fmaxf(m1, hi_bf(v.x));
                        m2 = fmaxf(m2, lo_bf(v.y)); m3 = fmaxf(m3, hi_bf(v.y));
                    }
                    int cb = round * 32 + sp * 8 + h2 * 4;
                    att_acc += att_w[cb] * m0 + att_w[cb + 1] * m1 + att_w[cb + 2] * m2 + att_w[cb + 3] * m3;
                }
            }
#pragma unroll
            for (int ts = 0; ts < 9; ++ts) {
                int kc = round * 9 + ts;
                bf16x8 bf[2];
#pragma unroll
                for (int nt = 0; nt < 2; ++nt)
                    bf[nt] = *(const bf16x8*)&col[(nt * 16 + l15) * COLP + ts * 32 + kb * 8];
#pragma unroll
                for (int mt = 0; mt < 2; ++mt) {
                    uint4 a = pw[(size_t)kc * 1024 + (wm + mt * 16 + l15) * 4 + kb];
                    bf16x8 af = __builtin_bit_cast(bf16x8, a);
#pragma unroll
                    for (int nt = 0; nt < 2; ++nt)
                        acc[mt][nt] = __builtin_amdgcn_mfma_f32_16x16x32_bf16(af, bf[nt], acc[mt][nt], 0, 0, 0);
                }
            }
        }
    }

    // finalize attention (wave 0), broadcast via LDS
    if (tid < 64) {
        float v = att_acc + __shfl_xor(att_acc, 1);
        if ((tid & 1) == 0) s_att[tid >> 1] = 1.f / (1.f + expf(-(v + att_b[0])));
    }
    __syncthreads();

    float attn[2];
#pragma unroll
    for (int nt = 0; nt < 2; ++nt) attn[nt] = s_att[nt * 16 + l15];

    // epilogue: scale by att, write out, GN partial sums
#pragma unroll
    for (int mt = 0; mt < 2; ++mt) {
        float s1 = 0.f, s2 = 0.f;
#pragma unroll
        for (int nt = 0; nt < 2; ++nt)
#pragma unroll
            for (int r = 0; r < 4; ++r) {
                float v = acc[mt][nt][r] * attn[nt];
                int m = wm + mt * 16 + kb * 4 + r;
                outp[(((size_t)(b * CT + m)) << 12) + h * 64 + n0 + nt * 16 + l15] = v;
                s1 += v; s2 += v * v;
            }
#pragma unroll
        for (int d = 1; d <= 16; d <<= 1) {
            s1 += __shfl_xor(s1, d);
            s2 += __shfl_xor(s2, d);
        }
        if ((lane & 31) == 0) {
            int gidx = w * 4 + mt * 2 + (kb >> 1);
            gnpart[blockIdx.x * 64 + gidx * 2] = s1;
            gnpart[blockIdx.x * 64 + gidx * 2 + 1] = s2;
        }
    }
}

// Fused GroupNorm: one block per (b,g); reduce 128 partial pairs -> stats -> normalize 32768 floats.
__global__ __launch_bounds__(256) void k_gn(const float* __restrict__ gnpart, const float* __restrict__ gamma,
                                            const float* __restrict__ beta, float* __restrict__ outp)
{
    __shared__ float rs1[128], rs2[128];
    __shared__ float s_stat[2];
    int bg = blockIdx.x;               // b = bg>>5, g = bg&31
    int b = bg >> 5, g = bg & 31;
    int tid = threadIdx.x;
    if (tid < 128) {
        int blk = (b * 64 + (tid >> 1)) * 2 + (tid & 1);
        rs1[tid] = gnpart[blk * 64 + g * 2];
        rs2[tid] = gnpart[blk * 64 + g * 2 + 1];
    }
    __syncthreads();
    if (tid < 64) {
        float a = rs1[tid] + rs1[tid + 64];
        float c = rs2[tid] + rs2[tid + 64];
#pragma unroll
        for (int d = 1; d <= 32; d <<= 1) {
            a += __shfl_xor(a, d);
            c += __shfl_xor(c, d);
        }
        if (tid == 0) {
            float mean = a * (1.f / 32768.f);
            float var = c * (1.f / 32768.f) - mean * mean;
            s_stat[0] = mean;
            s_stat[1] = rsqrtf(var + 1e-5f);
        }
    }
    __syncthreads();
    float mean = s_stat[0], rstd = s_stat[1];
    float4* p4 = (float4*)(outp + ((size_t)(b * CT + g * 8) << 12));
    for (int i = tid; i < 8192; i += 256) {
        int c = g * 8 + (i >> 10);
        float ga = gamma[c], be = beta[c];
        float4 v = p4[i];
        float4 r;
        r.x = fmaxf((v.x - mean) * rstd * ga + be, 0.f);
        r.y = fmaxf((v.y - mean) * rstd * ga + be, 0.f);
        r.z = fmaxf((v.z - mean) * rstd * ga + be, 0.f);
        r.w = fmaxf((v.w - mean) * rstd * ga + be, 0.f);
        p4[i] = r;
    }
}

extern "C" void kernel_launch(void* const* d_in, const int* in_sizes, int n_in,
                              void* d_out, int out_size, void* d_ws, size_t ws_size,
                              hipStream_t stream)
{
    const float* x = (const float*)d_in[0];
    const float* off = (const float*)d_in[1];
    const float* wgt = (const float*)d_in[2];
    const float* attw = (const float*)d_in[3];
    const float* attb = (const float*)d_in[4];
    const float* gamma = (const float*)d_in[5];
    const float* beta = (const float*)d_in[6];
    float* outp = (float*)d_out;

    char* ws = (char*)d_ws;
    uint4* xi = (uint4*)ws;                          // 8.39 MB
    uint4* pw = (uint4*)(ws + 8388608);              // 1.18 MB
    float* gnpart = (float*)(ws + 9568256);          // 512*64 f32 = 128 KB

    k_prep<<<dim3(2336), dim3(256), 0, stream>>>(x, xi, wgt, pw);
    k_main<<<dim3(512), dim3(512), 0, stream>>>(xi, off, pw, attw, attb, outp, gnpart);
    k_gn<<<dim3(128), dim3(256), 0, stream>>>(gnpart, gamma, beta, outp);
}

// Round 12
// 149.082 us; speedup vs baseline: 1.3681x; 1.0070x over previous
//
#include <hip/hip_runtime.h>

#define CT 256
#define KDIM 2304
#define COLP 296         // padded col row stride in shorts

typedef unsigned short u16;
typedef _Float16 h2 __attribute__((ext_vector_type(2)));
typedef _Float16 h8 __attribute__((ext_vector_type(8)));
typedef __attribute__((ext_vector_type(4))) float f32x4;

__device__ __forceinline__ unsigned pkh(float a, float b) {   // two f32 -> packed f16 (RTE)
    h2 r; r[0] = (_Float16)a; r[1] = (_Float16)b;
    return __builtin_bit_cast(unsigned, r);
}

// async global->LDS DMA, 16B per lane; LDS dest must be wave-uniform base + lane*16
__device__ __forceinline__ void gload_lds16(const uint4* g, u16* l) {
    __builtin_amdgcn_global_load_lds((const __attribute__((address_space(1))) void*)g,
                                     (__attribute__((address_space(3))) void*)l, 16, 0, 0);
}

// Fused prep: blocks [0,2048) = x -> xi (f16 interleaved-8); [2048,2336) = W -> pw (f16).
__global__ __launch_bounds__(256) void k_prep(const float* __restrict__ x, uint4* __restrict__ xi,
                                              const float* __restrict__ wgt, uint4* __restrict__ pw)
{
    if (blockIdx.x < 2048) {
        int u = blockIdx.x * 256 + threadIdx.x;        // [0, 524288)
        int bcg = u >> 12, p = u & 4095;
        const float* xp = x + (((size_t)bcg) << 15) + p;
        unsigned r[4];
#pragma unroll
        for (int i = 0; i < 4; ++i)
            r[i] = pkh(xp[(size_t)(2 * i) << 12], xp[(size_t)(2 * i + 1) << 12]);
        uint4 o; o.x = r[0]; o.y = r[1]; o.z = r[2]; o.w = r[3];
        xi[u] = o;
    } else {
        int u = (blockIdx.x - 2048) * 256 + threadIdx.x;   // [0, 73728)
        int kc = u >> 10, rm = u & 1023;
        int m = rm >> 2, j = rm & 3;
        int round = kc / 9, tap = kc - round * 9;
        const float* src = wgt + (size_t)m * KDIM + tap;
        int c0 = round * 32 + j * 8;
        unsigned q[4];
#pragma unroll
        for (int i = 0; i < 4; ++i)
            q[i] = pkh(src[(size_t)(c0 + 2 * i) * 9], src[(size_t)(c0 + 2 * i + 1) * 9]);
        uint4 o; o.x = q[0]; o.y = q[1]; o.z = q[2]; o.w = q[3];
        pw[u] = o;
    }
}

// one gather item: bilinear blend of 8 channels (packed f16), write 16B col entry
__device__ __forceinline__ void gather_one(int it2, int sp, int xsb, size_t gfall,
                                           const uint2* s_wt, const int2* s_off,
                                           const u16* Xs, u16* col,
                                           const uint4* __restrict__ xi, int rbase, int nw)
{
    int tap = it2 >> 5, nn = it2 & 31;
    uint2 wp = s_wt[it2];
    h2 w01 = __builtin_bit_cast(h2, wp.x);
    h2 w23 = __builtin_bit_cast(h2, wp.y);
    h2 wxp = (h2){w01[0], w01[0]}, wyp = (h2){w01[1], w01[1]};
    h2 wzp = (h2){w23[0], w23[0]}, wwp = (h2){w23[1], w23[1]};
    int2 of = s_off[it2];
    int P00 = of.x & 0xffff, P01 = (of.x >> 16) & 0xffff;
    int P10 = of.y & 0xffff, P11 = (of.y >> 16) & 0xffff;
    uint4 c00, c01, c10, c11;
    int Q;
    Q = P00 - rbase;
    if ((unsigned)Q < (unsigned)nw) c00 = *(const uint4*)&Xs[xsb + Q * 8]; else c00 = xi[gfall + P00];
    Q = P01 - rbase;
    if ((unsigned)Q < (unsigned)nw) c01 = *(const uint4*)&Xs[xsb + Q * 8]; else c01 = xi[gfall + P01];
    Q = P10 - rbase;
    if ((unsigned)Q < (unsigned)nw) c10 = *(const uint4*)&Xs[xsb + Q * 8]; else c10 = xi[gfall + P10];
    Q = P11 - rbase;
    if ((unsigned)Q < (unsigned)nw) c11 = *(const uint4*)&Xs[xsb + Q * 8]; else c11 = xi[gfall + P11];
    const unsigned* a00 = (const unsigned*)&c00;
    const unsigned* a01 = (const unsigned*)&c01;
    const unsigned* a10 = (const unsigned*)&c10;
    const unsigned* a11 = (const unsigned*)&c11;
    unsigned o[4];
#pragma unroll
    for (int q = 0; q < 4; ++q) {
        h2 r = wxp * __builtin_bit_cast(h2, a00[q]) + wyp * __builtin_bit_cast(h2, a01[q])
             + wzp * __builtin_bit_cast(h2, a10[q]) + wwp * __builtin_bit_cast(h2, a11[q]);
        o[q] = __builtin_bit_cast(unsigned, r);
    }
    uint4 ov; ov.x = o[0]; ov.y = o[1]; ov.z = o[2]; ov.w = o[3];
    *(uint4*)&col[nn * COLP + tap * 32 + sp * 8] = ov;
}

// Fused: deformable unfold (DMA-staged LDS gather, packed f16) + attention + MFMA GEMM + GN partials.
// Grid 512: bx = rowblk*2 + half; 512 threads = 8 waves.
__global__ __launch_bounds__(512, 2) void k_main(const uint4* __restrict__ xi, const float* __restrict__ off,
                                                 const uint4* __restrict__ pw, const float* __restrict__ att_w,
                                                 const float* __restrict__ att_b,
                                                 float* __restrict__ outp, float* __restrict__ gnpart)
{
    __shared__ uint2 s_wt[288];        // bilinear corner weights as 4 x f16
    __shared__ int2 s_off[288];        // packed corner positions
    __shared__ u16 Xs[4 * 6656];       // [buf][cgl] planes: <=13 rows x 64 pos x 8 ch each
    __shared__ u16 col[32 * COLP];     // 32 n x 288 k (padded), f16
    __shared__ float s_att[32];

    int rowblk = blockIdx.x >> 1, half = blockIdx.x & 1;
    int b = rowblk >> 6, h = rowblk & 63, n0 = half * 32;
    int tid = threadIdx.x;
    int lane = tid & 63, w = tid >> 6;
    int l15 = lane & 15, kb = lane >> 4;
    int wm = w * 32;

    // bilinear coords for this block's 32 positions
    for (int e = tid; e < 288; e += 512) {
        int kk = e >> 5, wl = e & 31;
        int ww_ = n0 + wl;
        int ky = kk / 3, kx = kk - ky * 3;
        float dy = off[((size_t)(b * 18 + 2 * kk) * 64 + h) * 64 + ww_];
        float dx = off[((size_t)(b * 18 + 2 * kk + 1) * 64 + h) * 64 + ww_];
        float py = (float)(h + ky - 1) + dy;
        float px = (float)(ww_ + kx - 1) + dx;
        float y0f = floorf(py), x0f = floorf(px);
        int y0 = (int)y0f, x0 = (int)x0f;
        float fy = py - y0f, fx = px - x0f;
        float vy0 = (y0 >= 0 && y0 < 64) ? 1.f : 0.f;
        float vy1 = (y0 >= -1 && y0 < 63) ? 1.f : 0.f;
        float vx0 = (x0 >= 0 && x0 < 64) ? 1.f : 0.f;
        float vx1 = (x0 >= -1 && x0 < 63) ? 1.f : 0.f;
        float w0 = (1.f - fy) * (1.f - fx) * vy0 * vx0;
        float w1 = (1.f - fy) * fx * vy0 * vx1;
        float w2 = fy * (1.f - fx) * vy1 * vx0;
        float w3 = fy * fx * vy1 * vx1;
        uint2 wp;
        wp.x = pkh(w0, w1);
        wp.y = pkh(w2, w3);
        int yc0 = min(max(y0, 0), 63), yc1 = min(max(y0 + 1, 0), 63);
        int xc0 = min(max(x0, 0), 63), xc1 = min(max(x0 + 1, 0), 63);
        s_wt[e] = wp;
        s_off[e] = make_int2((yc0 * 64 + xc0) | ((yc0 * 64 + xc1) << 16),
                             (yc1 * 64 + xc0) | ((yc1 * 64 + xc1) << 16));
    }

    int r0 = max(0, h - 6), r1 = min(63, h + 6);
    int nrows = r1 - r0 + 1, nw = nrows * 64, rbase = r0 * 64;
    size_t xib = (size_t)(b * 32) << 12;               // base of this image's 32 superplanes

    float att_acc = 0.f;
    f32x4 acc[2][2];
#pragma unroll
    for (int mt = 0; mt < 2; ++mt)
#pragma unroll
        for (int nt = 0; nt < 2; ++nt) acc[mt][nt] = (f32x4){0.f, 0.f, 0.f, 0.f};

    // issue DMA for stage 0 into buf 0
#pragma unroll
    for (int cgl = 0; cgl < 2; ++cgl)
        for (int e = tid; e < nw; e += 512)
            gload_lds16(&xi[xib + ((size_t)cgl << 12) + rbase + e], &Xs[(cgl * 6656 + e * 8)]);

    for (int stage = 0; stage < 16; ++stage) {
        int buf = stage & 1;
        int s2 = stage & 1;
        __syncthreads();               // Xs[buf] DMA drained; prev gather (read buf^1) done
        if (stage < 15) {              // DMA next stage into buf^1, covered by this gather
            size_t nb = xib + ((size_t)((stage + 1) * 2) << 12) + rbase;
#pragma unroll
            for (int cgl = 0; cgl < 2; ++cgl)
                for (int e = tid; e < nw; e += 512)
                    gload_lds16(&xi[nb + ((size_t)cgl << 12) + e],
                                &Xs[(((buf ^ 1) * 2 + cgl) * 6656 + e * 8)]);
        }
        // gather: 576 items = 2 cgs x 9 taps x 32 n; tail (64 items) on wave 7
        {
            int it = tid;
            int cgl = (it >= 288) ? 1 : 0;
            gather_one(it - cgl * 288, s2 * 2 + cgl, (buf * 2 + cgl) * 6656,
                       xib + ((size_t)(stage * 2 + cgl) << 12), s_wt, s_off, Xs, col, xi, rbase, nw);
            if (tid >= 448) {
                int it2 = tid + 64;    // [512, 576) -> cgl 1
                gather_one(it2 - 288, s2 * 2 + 1, (buf * 2 + 1) * 6656,
                           xib + ((size_t)(stage * 2 + 1) << 12), s_wt, s_off, Xs, col, xi, rbase, nw);
            }
        }

        if (stage & 1) {               // full 288-k col slice ready -> att + MFMA
            int round = stage >> 1;
            __syncthreads();

            // attention tap-max + dot: wave 0 only (others proceed to MFMA)
            if (tid < 64) {
                int nn = tid >> 1, h2i = tid & 1;
#pragma unroll
                for (int sp = 0; sp < 4; ++sp) {
                    const u16* base = &col[nn * COLP + sp * 8 + h2i * 4];
                    float m0 = -1e30f, m1 = -1e30f, m2 = -1e30f, m3 = -1e30f;
#pragma unroll
                    for (int t = 0; t < 9; ++t) {
                        uint2 v = *(const uint2*)(base + t * 32);
                        h2 va = __builtin_bit_cast(h2, v.x);
                        h2 vb = __builtin_bit_cast(h2, v.y);
                        m0 = fmaxf(m0, (float)va[0]); m1 = fmaxf(m1, (float)va[1]);
                        m2 = fmaxf(m2, (float)vb[0]); m3 = fmaxf(m3, (float)vb[1]);
                    }
                    int cb = round * 32 + sp * 8 + h2i * 4;
                    att_acc += att_w[cb] * m0 + att_w[cb + 1] * m1 + att_w[cb + 2] * m2 + att_w[cb + 3] * m3;
                }
            }
#pragma unroll
            for (int ts = 0; ts < 9; ++ts) {
                int kc = round * 9 + ts;
                h8 bf[2];
#pragma unroll
                for (int nt = 0; nt < 2; ++nt)
                    bf[nt] = *(const h8*)&col[(nt * 16 + l15) * COLP + ts * 32 + kb * 8];
#pragma unroll
                for (int mt = 0; mt < 2; ++mt) {
                    uint4 a = pw[(size_t)kc * 1024 + (wm + mt * 16 + l15) * 4 + kb];
                    h8 af = __builtin_bit_cast(h8, a);
#pragma unroll
                    for (int nt = 0; nt < 2; ++nt)
                        acc[mt][nt] = __builtin_amdgcn_mfma_f32_16x16x32_f16(af, bf[nt], acc[mt][nt], 0, 0, 0);
                }
            }
        }
    }

    // finalize attention (wave 0), broadcast via LDS
    if (tid < 64) {
        float v = att_acc + __shfl_xor(att_acc, 1);
        if ((tid & 1) == 0) s_att[tid >> 1] = 1.f / (1.f + expf(-(v + att_b[0])));
    }
    __syncthreads();

    float attn[2];
#pragma unroll
    for (int nt = 0; nt < 2; ++nt) attn[nt] = s_att[nt * 16 + l15];

    // epilogue: scale by att, write out, GN partial sums
#pragma unroll
    for (int mt = 0; mt < 2; ++mt) {
        float s1 = 0.f, s2 = 0.f;
#pragma unroll
        for (int nt = 0; nt < 2; ++nt)
#pragma unroll
            for (int r = 0; r < 4; ++r) {
                float v = acc[mt][nt][r] * attn[nt];
                int m = wm + mt * 16 + kb * 4 + r;
                outp[(((size_t)(b * CT + m)) << 12) + h * 64 + n0 + nt * 16 + l15] = v;
                s1 += v; s2 += v * v;
            }
#pragma unroll
        for (int d = 1; d <= 16; d <<= 1) {
            s1 += __shfl_xor(s1, d);
            s2 += __shfl_xor(s2, d);
        }
        if ((lane & 31) == 0) {
            int gidx = w * 4 + mt * 2 + (kb >> 1);
            gnpart[blockIdx.x * 64 + gidx * 2] = s1;
            gnpart[blockIdx.x * 64 + gidx * 2 + 1] = s2;
        }
    }
}

// Fused GroupNorm: one block per (b,g); reduce 128 partial pairs -> stats -> normalize 32768 floats.
__global__ __launch_bounds__(256) void k_gn(const float* __restrict__ gnpart, const float* __restrict__ gamma,
                                            const float* __restrict__ beta, float* __restrict__ outp)
{
    __shared__ float rs1[128], rs2[128];
    __shared__ float s_stat[2];
    int bg = blockIdx.x;               // b = bg>>5, g = bg&31
    int b = bg >> 5, g = bg & 31;
    int tid = threadIdx.x;
    if (tid < 128) {
        int blk = (b * 64 + (tid >> 1)) * 2 + (tid & 1);
        rs1[tid] = gnpart[blk * 64 + g * 2];
        rs2[tid] = gnpart[blk * 64 + g * 2 + 1];
    }
    __syncthreads();
    if (tid < 64) {
        float a = rs1[tid] + rs1[tid + 64];
        float c = rs2[tid] + rs2[tid + 64];
#pragma unroll
        for (int d = 1; d <= 32; d <<= 1) {
            a += __shfl_xor(a, d);
            c += __shfl_xor(c, d);
        }
        if (tid == 0) {
            float mean = a * (1.f / 32768.f);
            float var = c * (1.f / 32768.f) - mean * mean;
            s_stat[0] = mean;
            s_stat[1] = rsqrtf(var + 1e-5f);
        }
    }
    __syncthreads();
    float mean = s_stat[0], rstd = s_stat[1];
    float4* p4 = (float4*)(outp + ((size_t)(b * CT + g * 8) << 12));
    for (int i = tid; i < 8192; i += 256) {
        int c = g * 8 + (i >> 10);
        float ga = gamma[c], be = beta[c];
        float4 v = p4[i];
        float4 r;
        r.x = fmaxf((v.x - mean) * rstd * ga + be, 0.f);
        r.y = fmaxf((v.y - mean) * rstd * ga + be, 0.f);
        r.z = fmaxf((v.z - mean) * rstd * ga + be, 0.f);
        r.w = fmaxf((v.w - mean) * rstd * ga + be, 0.f);
        p4[i] = r;
    }
}

extern "C" void kernel_launch(void* const* d_in, const int* in_sizes, int n_in,
                              void* d_out, int out_size, void* d_ws, size_t ws_size,
                              hipStream_t stream)
{
    const float* x = (const float*)d_in[0];
    const float* off = (const float*)d_in[1];
    const float* wgt = (const float*)d_in[2];
    const float* attw = (const float*)d_in[3];
    const float* attb = (const float*)d_in[4];
    const float* gamma = (const float*)d_in[5];
    const float* beta = (const float*)d_in[6];
    float* outp = (float*)d_out;

    char* ws = (char*)d_ws;
    uint4* xi = (uint4*)ws;                          // 8.39 MB
    uint4* pw = (uint4*)(ws + 8388608);              // 1.18 MB
    float* gnpart = (float*)(ws + 9568256);          // 512*64 f32 = 128 KB

    k_prep<<<dim3(2336), dim3(256), 0, stream>>>(x, xi, wgt, pw);
    k_main<<<dim3(512), dim3(512), 0, stream>>>(xi, off, pw, attw, attb, outp, gnpart);
    k_gn<<<dim3(128), dim3(256), 0, stream>>>(gnpart, gamma, beta, outp);
}

// Round 13
// 147.058 us; speedup vs baseline: 1.3869x; 1.0138x over previous
//
#include <hip/hip_runtime.h>

#define CT 256
#define KDIM 2304
#define COLP 296         // padded col row stride in shorts

typedef unsigned short u16;
typedef _Float16 h2 __attribute__((ext_vector_type(2)));
typedef _Float16 h8 __attribute__((ext_vector_type(8)));
typedef __attribute__((ext_vector_type(4))) float f32x4;

__device__ __forceinline__ unsigned pkh(float a, float b) {   // two f32 -> packed f16 (RTE)
    h2 r; r[0] = (_Float16)a; r[1] = (_Float16)b;
    return __builtin_bit_cast(unsigned, r);
}

// async global->LDS DMA, 16B per lane; LDS dest must be wave-uniform base + lane*16
__device__ __forceinline__ void gload_lds16(const uint4* g, u16* l) {
    __builtin_amdgcn_global_load_lds((const __attribute__((address_space(1))) void*)g,
                                     (__attribute__((address_space(3))) void*)l, 16, 0, 0);
}

// Fused prep: blocks [0,2048) = x -> xi (f16 interleaved-8); [2048,2336) = W -> pw (f16).
__global__ __launch_bounds__(256) void k_prep(const float* __restrict__ x, uint4* __restrict__ xi,
                                              const float* __restrict__ wgt, uint4* __restrict__ pw)
{
    if (blockIdx.x < 2048) {
        int u = blockIdx.x * 256 + threadIdx.x;        // [0, 524288)
        int bcg = u >> 12, p = u & 4095;
        const float* xp = x + (((size_t)bcg) << 15) + p;
        unsigned r[4];
#pragma unroll
        for (int i = 0; i < 4; ++i)
            r[i] = pkh(xp[(size_t)(2 * i) << 12], xp[(size_t)(2 * i + 1) << 12]);
        uint4 o; o.x = r[0]; o.y = r[1]; o.z = r[2]; o.w = r[3];
        xi[u] = o;
    } else {
        int u = (blockIdx.x - 2048) * 256 + threadIdx.x;   // [0, 73728)
        int kc = u >> 10, rm = u & 1023;
        int m = rm >> 2, j = rm & 3;
        int round = kc / 9, tap = kc - round * 9;
        const float* src = wgt + (size_t)m * KDIM + tap;
        int c0 = round * 32 + j * 8;
        unsigned q[4];
#pragma unroll
        for (int i = 0; i < 4; ++i)
            q[i] = pkh(src[(size_t)(c0 + 2 * i) * 9], src[(size_t)(c0 + 2 * i + 1) * 9]);
        uint4 o; o.x = q[0]; o.y = q[1]; o.z = q[2]; o.w = q[3];
        pw[u] = o;
    }
}

// one gather item: bilinear blend of 8 channels (packed f16), write 16B col entry
__device__ __forceinline__ void gather_one(int it2, int sp, int xsb, size_t gfall,
                                           const uint2* s_wt, const int2* s_off,
                                           const u16* Xs, u16* col,
                                           const uint4* __restrict__ xi, int rbase, int nw)
{
    int tap = it2 >> 5, nn = it2 & 31;
    uint2 wp = s_wt[it2];
    h2 w01 = __builtin_bit_cast(h2, wp.x);
    h2 w23 = __builtin_bit_cast(h2, wp.y);
    h2 wxp = (h2){w01[0], w01[0]}, wyp = (h2){w01[1], w01[1]};
    h2 wzp = (h2){w23[0], w23[0]}, wwp = (h2){w23[1], w23[1]};
    int2 of = s_off[it2];
    int P00 = of.x & 0xffff, P01 = (of.x >> 16) & 0xffff;
    int P10 = of.y & 0xffff, P11 = (of.y >> 16) & 0xffff;
    uint4 c00, c01, c10, c11;
    int Q;
    Q = P00 - rbase;
    if ((unsigned)Q < (unsigned)nw) c00 = *(const uint4*)&Xs[xsb + Q * 8]; else c00 = xi[gfall + P00];
    Q = P01 - rbase;
    if ((unsigned)Q < (unsigned)nw) c01 = *(const uint4*)&Xs[xsb + Q * 8]; else c01 = xi[gfall + P01];
    Q = P10 - rbase;
    if ((unsigned)Q < (unsigned)nw) c10 = *(const uint4*)&Xs[xsb + Q * 8]; else c10 = xi[gfall + P10];
    Q = P11 - rbase;
    if ((unsigned)Q < (unsigned)nw) c11 = *(const uint4*)&Xs[xsb + Q * 8]; else c11 = xi[gfall + P11];
    const unsigned* a00 = (const unsigned*)&c00;
    const unsigned* a01 = (const unsigned*)&c01;
    const unsigned* a10 = (const unsigned*)&c10;
    const unsigned* a11 = (const unsigned*)&c11;
    unsigned o[4];
#pragma unroll
    for (int q = 0; q < 4; ++q) {
        h2 r = wxp * __builtin_bit_cast(h2, a00[q]) + wyp * __builtin_bit_cast(h2, a01[q])
             + wzp * __builtin_bit_cast(h2, a10[q]) + wwp * __builtin_bit_cast(h2, a11[q]);
        o[q] = __builtin_bit_cast(unsigned, r);
    }
    uint4 ov; ov.x = o[0]; ov.y = o[1]; ov.z = o[2]; ov.w = o[3];
    *(uint4*)&col[nn * COLP + tap * 32 + sp * 8] = ov;
}

// Fused: deformable unfold (DMA-staged LDS gather, packed f16) + attention (all-wave) +
// MFMA GEMM (register-pipelined A-stream) + GN partials. Grid 512; 512 threads = 8 waves.
__global__ __launch_bounds__(512, 2) void k_main(const uint4* __restrict__ xi, const float* __restrict__ off,
                                                 const uint4* __restrict__ pw, const float* __restrict__ att_w,
                                                 const float* __restrict__ att_b,
                                                 float* __restrict__ outp, float* __restrict__ gnpart)
{
    __shared__ uint2 s_wt[288];        // bilinear corner weights as 4 x f16
    __shared__ int2 s_off[288];        // packed corner positions
    __shared__ u16 Xs[4 * 6656];       // [buf][cgl] planes: <=13 rows x 64 pos x 8 ch each
    __shared__ u16 col[32 * COLP];     // 32 n x 288 k (padded), f16
    __shared__ float s_att[32];

    int rowblk = blockIdx.x >> 1, half = blockIdx.x & 1;
    int b = rowblk >> 6, h = rowblk & 63, n0 = half * 32;
    int tid = threadIdx.x;
    int lane = tid & 63, w = tid >> 6;
    int l15 = lane & 15, kb = lane >> 4;
    int wm = w * 32;
    // attention assignment: wave w owns positions 4w..4w+3; lane -> (pos, channel-pair)
    int nn_a = w * 4 + (lane >> 4);
    int ca = (lane & 15) * 2;          // round-local channel pair

    // bilinear coords for this block's 32 positions
    for (int e = tid; e < 288; e += 512) {
        int kk = e >> 5, wl = e & 31;
        int ww_ = n0 + wl;
        int ky = kk / 3, kx = kk - ky * 3;
        float dy = off[((size_t)(b * 18 + 2 * kk) * 64 + h) * 64 + ww_];
        float dx = off[((size_t)(b * 18 + 2 * kk + 1) * 64 + h) * 64 + ww_];
        float py = (float)(h + ky - 1) + dy;
        float px = (float)(ww_ + kx - 1) + dx;
        float y0f = floorf(py), x0f = floorf(px);
        int y0 = (int)y0f, x0 = (int)x0f;
        float fy = py - y0f, fx = px - x0f;
        float vy0 = (y0 >= 0 && y0 < 64) ? 1.f : 0.f;
        float vy1 = (y0 >= -1 && y0 < 63) ? 1.f : 0.f;
        float vx0 = (x0 >= 0 && x0 < 64) ? 1.f : 0.f;
        float vx1 = (x0 >= -1 && x0 < 63) ? 1.f : 0.f;
        float w0 = (1.f - fy) * (1.f - fx) * vy0 * vx0;
        float w1 = (1.f - fy) * fx * vy0 * vx1;
        float w2 = fy * (1.f - fx) * vy1 * vx0;
        float w3 = fy * fx * vy1 * vx1;
        uint2 wp;
        wp.x = pkh(w0, w1);
        wp.y = pkh(w2, w3);
        int yc0 = min(max(y0, 0), 63), yc1 = min(max(y0 + 1, 0), 63);
        int xc0 = min(max(x0, 0), 63), xc1 = min(max(x0 + 1, 0), 63);
        s_wt[e] = wp;
        s_off[e] = make_int2((yc0 * 64 + xc0) | ((yc0 * 64 + xc1) << 16),
                             (yc1 * 64 + xc0) | ((yc1 * 64 + xc1) << 16));
    }

    int r0 = max(0, h - 6), r1 = min(63, h + 6);
    int nrows = r1 - r0 + 1, nw = nrows * 64, rbase = r0 * 64;
    size_t xib = (size_t)(b * 32) << 12;               // base of this image's 32 superplanes

    float att_acc = 0.f;
    f32x4 acc[2][2];
#pragma unroll
    for (int mt = 0; mt < 2; ++mt)
#pragma unroll
        for (int nt = 0; nt < 2; ++nt) acc[mt][nt] = (f32x4){0.f, 0.f, 0.f, 0.f};

    int pwoff[2];
#pragma unroll
    for (int mt = 0; mt < 2; ++mt) pwoff[mt] = (wm + mt * 16 + l15) * 4 + kb;

    // issue DMA for stage 0 into buf 0
#pragma unroll
    for (int cgl = 0; cgl < 2; ++cgl)
        for (int e = tid; e < nw; e += 512)
            gload_lds16(&xi[xib + ((size_t)cgl << 12) + rbase + e], &Xs[(cgl * 6656 + e * 8)]);

    for (int stage = 0; stage < 16; ++stage) {
        int buf = stage & 1;
        int s2 = stage & 1;
        __syncthreads();               // Xs[buf] DMA drained; prev gather (read buf^1) done
        if (stage < 15) {              // DMA next stage into buf^1, covered by this gather
            size_t nb = xib + ((size_t)((stage + 1) * 2) << 12) + rbase;
#pragma unroll
            for (int cgl = 0; cgl < 2; ++cgl)
                for (int e = tid; e < nw; e += 512)
                    gload_lds16(&xi[nb + ((size_t)cgl << 12) + e],
                                &Xs[(((buf ^ 1) * 2 + cgl) * 6656 + e * 8)]);
        }
        // gather: 576 items = 2 cgs x 9 taps x 32 n; tail (64 items) on wave 7
        {
            int it = tid;
            int cgl = (it >= 288) ? 1 : 0;
            gather_one(it - cgl * 288, s2 * 2 + cgl, (buf * 2 + cgl) * 6656,
                       xib + ((size_t)(stage * 2 + cgl) << 12), s_wt, s_off, Xs, col, xi, rbase, nw);
            if (tid >= 448) {
                int it2 = tid + 64;    // [512, 576) -> cgl 1
                gather_one(it2 - 288, s2 * 2 + 1, (buf * 2 + 1) * 6656,
                           xib + ((size_t)(stage * 2 + 1) << 12), s_wt, s_off, Xs, col, xi, rbase, nw);
            }
        }

        if (stage & 1) {               // full 288-k col slice ready -> att + MFMA
            int round = stage >> 1;
            __syncthreads();

            // batch A-stream start: preload first 4 k-steps (latency hidden behind att + b reads)
            uint4 aa[4][2];
#pragma unroll
            for (int ts = 0; ts < 4; ++ts)
#pragma unroll
                for (int mt = 0; mt < 2; ++mt)
                    aa[ts][mt] = pw[(size_t)(round * 9 + ts) * 1024 + pwoff[mt]];

            // attention tap-max + dot: all waves; this lane covers (nn_a, channels ca,ca+1)
            {
                int sp = ca >> 3, co = ca & 7;
                const u16* base = &col[nn_a * COLP + sp * 8 + co];
                float m0 = -1e30f, m1 = -1e30f;
#pragma unroll
                for (int t = 0; t < 9; ++t) {
                    unsigned v = *(const unsigned*)(base + t * 32);
                    h2 vv = __builtin_bit_cast(h2, v);
                    m0 = fmaxf(m0, (float)vv[0]);
                    m1 = fmaxf(m1, (float)vv[1]);
                }
                int cb = round * 32 + ca;
                att_acc += att_w[cb] * m0 + att_w[cb + 1] * m1;
            }

            // MFMA with rolling 4-deep A buffer
#pragma unroll
            for (int ts = 0; ts < 9; ++ts) {
                h8 bf[2];
#pragma unroll
                for (int nt = 0; nt < 2; ++nt)
                    bf[nt] = *(const h8*)&col[(nt * 16 + l15) * COLP + ts * 32 + kb * 8];
                h8 af[2];
#pragma unroll
                for (int mt = 0; mt < 2; ++mt) af[mt] = __builtin_bit_cast(h8, aa[ts & 3][mt]);
                if (ts + 4 < 9) {
#pragma unroll
                    for (int mt = 0; mt < 2; ++mt)
                        aa[ts & 3][mt] = pw[(size_t)(round * 9 + ts + 4) * 1024 + pwoff[mt]];
                }
#pragma unroll
                for (int mt = 0; mt < 2; ++mt)
#pragma unroll
                    for (int nt = 0; nt < 2; ++nt)
                        acc[mt][nt] = __builtin_amdgcn_mfma_f32_16x16x32_f16(af[mt], bf[nt], acc[mt][nt], 0, 0, 0);
            }
        }
    }

    // finalize attention: reduce over the 16 lanes sharing nn_a, sigmoid, broadcast
#pragma unroll
    for (int d = 1; d <= 8; d <<= 1) att_acc += __shfl_xor(att_acc, d);
    if ((lane & 15) == 0) s_att[nn_a] = 1.f / (1.f + expf(-(att_acc + att_b[0])));
    __syncthreads();

    float attn[2];
#pragma unroll
    for (int nt = 0; nt < 2; ++nt) attn[nt] = s_att[nt * 16 + l15];

    // epilogue: scale by att, write out, GN partial sums
#pragma unroll
    for (int mt = 0; mt < 2; ++mt) {
        float s1 = 0.f, s2 = 0.f;
#pragma unroll
        for (int nt = 0; nt < 2; ++nt)
#pragma unroll
            for (int r = 0; r < 4; ++r) {
                float v = acc[mt][nt][r] * attn[nt];
                int m = wm + mt * 16 + kb * 4 + r;
                outp[(((size_t)(b * CT + m)) << 12) + h * 64 + n0 + nt * 16 + l15] = v;
                s1 += v; s2 += v * v;
            }
#pragma unroll
        for (int d = 1; d <= 16; d <<= 1) {
            s1 += __shfl_xor(s1, d);
            s2 += __shfl_xor(s2, d);
        }
        if ((lane & 31) == 0) {
            int gidx = w * 4 + mt * 2 + (kb >> 1);
            gnpart[blockIdx.x * 64 + gidx * 2] = s1;
            gnpart[blockIdx.x * 64 + gidx * 2 + 1] = s2;
        }
    }
}

// Fused GroupNorm: one block per (b,g); reduce 128 partial pairs -> stats -> normalize 32768 floats.
__global__ __launch_bounds__(256) void k_gn(const float* __restrict__ gnpart, const float* __restrict__ gamma,
                                            const float* __restrict__ beta, float* __restrict__ outp)
{
    __shared__ float rs1[128], rs2[128];
    __shared__ float s_stat[2];
    int bg = blockIdx.x;               // b = bg>>5, g = bg&31
    int b = bg >> 5, g = bg & 31;
    int tid = threadIdx.x;
    if (tid < 128) {
        int blk = (b * 64 + (tid >> 1)) * 2 + (tid & 1);
        rs1[tid] = gnpart[blk * 64 + g * 2];
        rs2[tid] = gnpart[blk * 64 + g * 2 + 1];
    }
    __syncthreads();
    if (tid < 64) {
        float a = rs1[tid] + rs1[tid + 64];
        float c = rs2[tid] + rs2[tid + 64];
#pragma unroll
        for (int d = 1; d <= 32; d <<= 1) {
            a += __shfl_xor(a, d);
            c += __shfl_xor(c, d);
        }
        if (tid == 0) {
            float mean = a * (1.f / 32768.f);
            float var = c * (1.f / 32768.f) - mean * mean;
            s_stat[0] = mean;
            s_stat[1] = rsqrtf(var + 1e-5f);
        }
    }
    __syncthreads();
    float mean = s_stat[0], rstd = s_stat[1];
    float4* p4 = (float4*)(outp + ((size_t)(b * CT + g * 8) << 12));
    for (int i = tid; i < 8192; i += 256) {
        int c = g * 8 + (i >> 10);
        float ga = gamma[c], be = beta[c];
        float4 v = p4[i];
        float4 r;
        r.x = fmaxf((v.x - mean) * rstd * ga + be, 0.f);
        r.y = fmaxf((v.y - mean) * rstd * ga + be, 0.f);
        r.z = fmaxf((v.z - mean) * rstd * ga + be, 0.f);
        r.w = fmaxf((v.w - mean) * rstd * ga + be, 0.f);
        p4[i] = r;
    }
}

extern "C" void kernel_launch(void* const* d_in, const int* in_sizes, int n_in,
                              void* d_out, int out_size, void* d_ws, size_t ws_size,
                              hipStream_t stream)
{
    const float* x = (const float*)d_in[0];
    const float* off = (const float*)d_in[1];
    const float* wgt = (const float*)d_in[2];
    const float* attw = (const float*)d_in[3];
    const float* attb = (const float*)d_in[4];
    const float* gamma = (const float*)d_in[5];
    const float* beta = (const float*)d_in[6];
    float* outp = (float*)d_out;

    char* ws = (char*)d_ws;
    uint4* xi = (uint4*)ws;                          // 8.39 MB
    uint4* pw = (uint4*)(ws + 8388608);              // 1.18 MB
    float* gnpart = (float*)(ws + 9568256);          // 512*64 f32 = 128 KB

    k_prep<<<dim3(2336), dim3(256), 0, stream>>>(x, xi, wgt, pw);
    k_main<<<dim3(512), dim3(512), 0, stream>>>(xi, off, pw, attw, attb, outp, gnpart);
    k_gn<<<dim3(128), dim3(256), 0, stream>>>(gnpart, gamma, beta, outp);
}